// Round 5
// baseline (254.868 us; speedup 1.0000x reference)
//
#include <hip/hip_runtime.h>

#define IN_CH   128
#define OUT_CH  64
#define M_TILE  128         // nodes per block in the MFMA GEMM
#define XS_PITCH 136        // 128 bf16 + 8 pad (272 B row) -> conflict-free frags

typedef __attribute__((ext_vector_type(8))) short short8;
typedef __attribute__((ext_vector_type(4))) float floatx4;

__device__ __forceinline__ unsigned short f2bf(float f) {
    union { float f; unsigned u; } v; v.f = f;
    unsigned r = v.u + 0x7fffu + ((v.u >> 16) & 1u);   // RNE
    return (unsigned short)(r >> 16);
}
__device__ __forceinline__ float bf2f(unsigned v) {
    union { unsigned u; float f; } c; c.u = v << 16;
    return c.f;
}

// ---------------------------------------------------------------------------
// Kernel 1 (prep): CSR row pointers (lower_bound over sorted targets) for both
// edge sets, PLUS bf16 pre-pack of the combined transposed weights
// WcT[n][k] = bf16(Wc[k][n]), Wc = [Wmi+Ws | Wmo+Ws]  (128x128).
// ---------------------------------------------------------------------------
__global__ void prep_kernel(const int* __restrict__ tgtIn,
                            const int* __restrict__ tgtOut,
                            const float* __restrict__ Wmi,
                            const float* __restrict__ Wmo,
                            const float* __restrict__ Wsh,
                            int* __restrict__ rpIn,
                            int* __restrict__ rpOut,
                            unsigned short* __restrict__ WcT,
                            int n_nodes, int neIn, int neOut)
{
    int i = blockIdx.x * blockDim.x + threadIdx.x;
    int half = n_nodes + 1;
    if (i < 2 * half) {
        const int* tgt; int* rp; int t; int ne;
        if (i < half) { tgt = tgtIn;  rp = rpIn;  t = i;        ne = neIn; }
        else          { tgt = tgtOut; rp = rpOut; t = i - half; ne = neOut; }
        int lo = 0, hi = ne;
        while (lo < hi) {
            int mid = (lo + hi) >> 1;
            if (tgt[mid] < t) lo = mid + 1; else hi = mid;
        }
        rp[t] = lo;
    } else {
        int j = i - 2 * half;
        if (j < 2 * OUT_CH * IN_CH) {
            int n = j >> 7, k = j & 127;     // n: output col of Wc, k: input ch
            float m = (n < OUT_CH) ? Wmi[k * OUT_CH + n]
                                   : Wmo[k * OUT_CH + (n - OUT_CH)];
            float s = Wsh[k * OUT_CH + (n & (OUT_CH - 1))];
            WcT[n * IN_CH + k] = f2bf(m + s);
        }
    }
}

// ---------------------------------------------------------------------------
// Kernel 2 (MFMA GEMM): H = x_bf16 @ WcT^T. Block = 256 thr (4 waves),
// tile M=128 x N=128, K=128. Wave w -> cols [w*32, w*32+32): waves 0,1 -> A,
// waves 2,3 -> B. B-fragments loaded straight from global WcT (32 KB, L2-hot);
// only the x tile goes through LDS.
// ---------------------------------------------------------------------------
__global__ __launch_bounds__(256, 3)
void gemm_kernel(const float* __restrict__ x,
                 const unsigned short* __restrict__ WcT,
                 unsigned short* __restrict__ Abf,
                 unsigned short* __restrict__ Bbf,
                 int n_nodes)
{
    __shared__ unsigned short Xs[M_TILE][XS_PITCH];   // 34.8 KB

    const int tid  = threadIdx.x;
    const int w    = tid >> 6;
    const int lane = tid & 63;
    const int l15  = lane & 15;
    const int quad = lane >> 4;
    const long long node0 = (long long)blockIdx.x * M_TILE;

    // B-fragments: lane l15 holds WcT[n = w*32 + ni*16 + l15][k0 .. k0+8)
    short8 bfrag[4][2];
#pragma unroll
    for (int ks = 0; ks < 4; ++ks)
#pragma unroll
        for (int ni = 0; ni < 2; ++ni)
            bfrag[ks][ni] = *(const short8*)&WcT[(w * 32 + ni * 16 + l15) * IN_CH
                                                 + ks * 32 + quad * 8];

    // Stage x tile as bf16 (float4 reads, uint2 LDS writes). 16 iters/thread.
    {
        const float4* x4 = (const float4*)x;
        for (int i = tid; i < M_TILE * (IN_CH / 4); i += 256) {
            int row = i >> 5, c4 = i & 31;
            long long node = node0 + row;
            float4 v = make_float4(0.f, 0.f, 0.f, 0.f);
            if (node < n_nodes) v = x4[node * (IN_CH / 4) + c4];
            uint2 p;
            p.x = ((unsigned)f2bf(v.y) << 16) | f2bf(v.x);
            p.y = ((unsigned)f2bf(v.w) << 16) | f2bf(v.z);
            *(uint2*)&Xs[row][c4 * 4] = p;
        }
    }
    __syncthreads();

    floatx4 acc[8][2];
#pragma unroll
    for (int mi = 0; mi < 8; ++mi)
#pragma unroll
        for (int ni = 0; ni < 2; ++ni)
            acc[mi][ni] = (floatx4){0.f, 0.f, 0.f, 0.f};

#pragma unroll
    for (int ks = 0; ks < 4; ++ks) {
        const int k0 = ks * 32 + quad * 8;
#pragma unroll
        for (int mi = 0; mi < 8; ++mi) {
            short8 a = *(const short8*)&Xs[mi * 16 + l15][k0];
            acc[mi][0] = __builtin_amdgcn_mfma_f32_16x16x32_bf16(a, bfrag[ks][0], acc[mi][0], 0, 0, 0);
            acc[mi][1] = __builtin_amdgcn_mfma_f32_16x16x32_bf16(a, bfrag[ks][1], acc[mi][1], 0, 0, 0);
        }
    }

    // Epilogue: C/D layout col = lane&15, row = quad*4 + r.
    unsigned short* Hout = (w < 2) ? Abf : Bbf;
    const int colb = (w & 1) * 32;
#pragma unroll
    for (int mi = 0; mi < 8; ++mi)
#pragma unroll
        for (int ni = 0; ni < 2; ++ni)
#pragma unroll
            for (int r = 0; r < 4; ++r) {
                long long row = node0 + mi * 16 + quad * 4 + r;
                if (row < n_nodes)
                    Hout[row * OUT_CH + colb + ni * 16 + l15] = f2bf(acc[mi][ni][r]);
            }
}

// ---------------------------------------------------------------------------
// Kernel 3: segmented weighted gather-sum (bf16 H) + epilogue.
// TWO waves per node: even wave sums the in-segment over A, odd wave the
// out-segment over B; combined via LDS. Edge index e is wave-uniform, so
// src[e]/ew[e] are uniform scalar loads (s_load -> SGPR) and the gather is
// saddr-form global_load_ushort with a constant lane*2 voffset: per edge
// ~2 VALU (cvt + fmac-with-SGPR-w) + 1 VMEM; addressing is pure SALU.
// ---------------------------------------------------------------------------
__device__ __forceinline__
float segsum(const unsigned short* __restrict__ H, int e0, int e1,
             const int* __restrict__ src, const float* __restrict__ ew,
             int lane)
{
    float a0 = 0.f, a1 = 0.f, a2 = 0.f, a3 = 0.f;
    int e = e0;
    for (; e + 4 <= e1; e += 4) {
        int   s0 = src[e + 0], s1 = src[e + 1], s2 = src[e + 2], s3 = src[e + 3];
        float w0 = ew[e + 0],  w1 = ew[e + 1],  w2 = ew[e + 2],  w3 = ew[e + 3];
        float v0 = bf2f(H[s0 * OUT_CH + lane]);
        float v1 = bf2f(H[s1 * OUT_CH + lane]);
        float v2 = bf2f(H[s2 * OUT_CH + lane]);
        float v3 = bf2f(H[s3 * OUT_CH + lane]);
        a0 += w0 * v0; a1 += w1 * v1; a2 += w2 * v2; a3 += w3 * v3;
    }
    for (; e < e1; ++e) {
        float v = bf2f(H[src[e] * OUT_CH + lane]);
        a0 += ew[e] * v;
    }
    return (a0 + a1) + (a2 + a3);
}

__global__ __launch_bounds__(256)
void prop_kernel(const unsigned short* __restrict__ A,
                 const unsigned short* __restrict__ B,
                 const int* __restrict__ rpIn, const int* __restrict__ rpOut,
                 const int* __restrict__ srcIn, const float* __restrict__ ewIn,
                 const int* __restrict__ srcOut, const float* __restrict__ ewOut,
                 const float* __restrict__ bmi, const float* __restrict__ bmo,
                 const float* __restrict__ bsi, const float* __restrict__ bso,
                 const float* __restrict__ Cin, const float* __restrict__ Cout,
                 float* __restrict__ out, int n_nodes)
{
    __shared__ float xch[2][OUT_CH];

    const int lane = threadIdx.x & 63;
    const int wv   = threadIdx.x >> 6;   // 0..3
    const int slot = wv >> 1;            // node slot within block
    const int isB  = wv & 1;             // 0: in-segment/A, 1: out-segment/B
    const int t = blockIdx.x * 2 + slot;
    const bool valid = (t < n_nodes);

    float acc = 0.f;
    if (valid) {
        const unsigned short* H = isB ? B : A;
        const int*   rp  = isB ? rpOut : rpIn;
        const int*   src = isB ? srcOut : srcIn;
        const float* ew  = isB ? ewOut : ewIn;
        int e0 = __builtin_amdgcn_readfirstlane(rp[t]);
        int e1 = __builtin_amdgcn_readfirstlane(rp[t + 1]);
        acc = segsum(H, e0, e1, src, ew, lane);
    }

    if (isB) xch[slot][lane] = acc;
    __syncthreads();

    if (!isB && valid) {
        float oc = xch[slot][lane];
        float bin  = bmi[lane] + bsi[lane];
        float bout = bmo[lane] + bso[lane];
        out[t * OUT_CH + lane] = Cin[t] * (acc + bin) + Cout[t] * (oc + bout);
    }
}

// ---------------------------------------------------------------------------
extern "C" void kernel_launch(void* const* d_in, const int* in_sizes, int n_in,
                              void* d_out, int out_size, void* d_ws, size_t ws_size,
                              hipStream_t stream)
{
    const float* x    = (const float*)d_in[0];
    const float* Wmi  = (const float*)d_in[1];
    const float* Wmo  = (const float*)d_in[2];
    const float* Wsh  = (const float*)d_in[3];
    const float* bmi  = (const float*)d_in[4];
    const float* bmo  = (const float*)d_in[5];
    const float* bsi  = (const float*)d_in[6];
    const float* bso  = (const float*)d_in[7];
    const float* Cin  = (const float*)d_in[8];
    const float* Cout = (const float*)d_in[9];
    const int*   eiIn  = (const int*)d_in[10];
    const float* ewIn  = (const float*)d_in[11];
    const int*   eiOut = (const int*)d_in[12];
    const float* ewOut = (const float*)d_in[13];

    const int n_nodes = in_sizes[0] / IN_CH;   // 100000
    const int neIn  = in_sizes[11];            // 1000000
    const int neOut = in_sizes[13];

    const int* srcIn  = eiIn;                  // edge_index[0]
    const int* tgtIn  = eiIn + neIn;           // edge_index[1] (sorted)
    const int* srcOut = eiOut;
    const int* tgtOut = eiOut + neOut;

    // Workspace layout: Abf (bf16) | Bbf (bf16) | rpIn | rpOut | WcT (bf16)
    char* ws = (char*)d_ws;
    size_t NH = (size_t)n_nodes * OUT_CH * sizeof(unsigned short);
    unsigned short* Abf = (unsigned short*)ws;
    unsigned short* Bbf = (unsigned short*)(ws + NH);
    int* rpIn  = (int*)(ws + 2 * NH);
    int* rpOut = rpIn + (n_nodes + 1);
    unsigned short* WcT = (unsigned short*)(rpOut + (n_nodes + 1));

    // 1) rowptrs + combined-weight bf16 pre-pack
    int prep_threads = 2 * (n_nodes + 1) + 2 * OUT_CH * IN_CH;
    prep_kernel<<<(prep_threads + 255) / 256, 256, 0, stream>>>(
        tgtIn, tgtOut, Wmi, Wmo, Wsh, rpIn, rpOut, WcT, n_nodes, neIn, neOut);

    // 2) fused dense transform via MFMA (N=128 GEMM: [A|B] columns)
    int gblocks = (n_nodes + M_TILE - 1) / M_TILE;
    gemm_kernel<<<gblocks, 256, 0, stream>>>(x, WcT, Abf, Bbf, n_nodes);

    // 3) segmented gather-sum + epilogue (2 waves per node)
    prop_kernel<<<(n_nodes + 1) / 2, 256, 0, stream>>>(
        Abf, Bbf, rpIn, rpOut, srcIn, ewIn, srcOut, ewOut,
        bmi, bmo, bsi, bso, Cin, Cout, (float*)d_out, n_nodes);
}

// Round 6
// 197.487 us; speedup vs baseline: 1.2906x; 1.2906x over previous
//
#include <hip/hip_runtime.h>

#define IN_CH   128
#define OUT_CH  64
#define M_TILE  128         // nodes per block in the MFMA GEMM
#define XS_PITCH 136        // 128 bf16 + 8 pad (272 B row) -> conflict-free frags

typedef __attribute__((ext_vector_type(8))) short short8;
typedef __attribute__((ext_vector_type(4))) float floatx4;

__device__ __forceinline__ unsigned short f2bf(float f) {
    union { float f; unsigned u; } v; v.f = f;
    unsigned r = v.u + 0x7fffu + ((v.u >> 16) & 1u);   // RNE
    return (unsigned short)(r >> 16);
}

// ---------------------------------------------------------------------------
// Kernel 1 (prep): CSR row pointers (lower_bound over sorted targets) for both
// edge sets, PLUS bf16 pre-pack of the combined transposed weights
// WcT[n][k] = bf16(Wc[k][n]), Wc = [Wmi+Ws | Wmo+Ws]  (128x128).
// ---------------------------------------------------------------------------
__global__ void prep_kernel(const int* __restrict__ tgtIn,
                            const int* __restrict__ tgtOut,
                            const float* __restrict__ Wmi,
                            const float* __restrict__ Wmo,
                            const float* __restrict__ Wsh,
                            int* __restrict__ rpIn,
                            int* __restrict__ rpOut,
                            unsigned short* __restrict__ WcT,
                            int n_nodes, int neIn, int neOut)
{
    int i = blockIdx.x * blockDim.x + threadIdx.x;
    int half = n_nodes + 1;
    if (i < 2 * half) {
        const int* tgt; int* rp; int t; int ne;
        if (i < half) { tgt = tgtIn;  rp = rpIn;  t = i;        ne = neIn; }
        else          { tgt = tgtOut; rp = rpOut; t = i - half; ne = neOut; }
        int lo = 0, hi = ne;
        while (lo < hi) {
            int mid = (lo + hi) >> 1;
            if (tgt[mid] < t) lo = mid + 1; else hi = mid;
        }
        rp[t] = lo;
    } else {
        int j = i - 2 * half;
        if (j < 2 * OUT_CH * IN_CH) {
            int n = j >> 7, k = j & 127;     // n: output col of Wc, k: input ch
            float m = (n < OUT_CH) ? Wmi[k * OUT_CH + n]
                                   : Wmo[k * OUT_CH + (n - OUT_CH)];
            float s = Wsh[k * OUT_CH + (n & (OUT_CH - 1))];
            WcT[n * IN_CH + k] = f2bf(m + s);
        }
    }
}

// ---------------------------------------------------------------------------
// Kernel 2 (MFMA GEMM): H = x_bf16 @ WcT^T. Block = 256 thr (4 waves),
// tile M=128 x N=128, K=128. Waves 0,1 -> A cols, waves 2,3 -> B cols.
// B-fragments straight from global WcT (32 KB, L2-hot); x tile via LDS.
// ---------------------------------------------------------------------------
__global__ __launch_bounds__(256, 3)
void gemm_kernel(const float* __restrict__ x,
                 const unsigned short* __restrict__ WcT,
                 unsigned short* __restrict__ Abf,
                 unsigned short* __restrict__ Bbf,
                 int n_nodes)
{
    __shared__ unsigned short Xs[M_TILE][XS_PITCH];   // 34.8 KB

    const int tid  = threadIdx.x;
    const int w    = tid >> 6;
    const int lane = tid & 63;
    const int l15  = lane & 15;
    const int quad = lane >> 4;
    const long long node0 = (long long)blockIdx.x * M_TILE;

    short8 bfrag[4][2];
#pragma unroll
    for (int ks = 0; ks < 4; ++ks)
#pragma unroll
        for (int ni = 0; ni < 2; ++ni)
            bfrag[ks][ni] = *(const short8*)&WcT[(w * 32 + ni * 16 + l15) * IN_CH
                                                 + ks * 32 + quad * 8];

    {
        const float4* x4 = (const float4*)x;
        for (int i = tid; i < M_TILE * (IN_CH / 4); i += 256) {
            int row = i >> 5, c4 = i & 31;
            long long node = node0 + row;
            float4 v = make_float4(0.f, 0.f, 0.f, 0.f);
            if (node < n_nodes) v = x4[node * (IN_CH / 4) + c4];
            uint2 p;
            p.x = ((unsigned)f2bf(v.y) << 16) | f2bf(v.x);
            p.y = ((unsigned)f2bf(v.w) << 16) | f2bf(v.z);
            *(uint2*)&Xs[row][c4 * 4] = p;
        }
    }
    __syncthreads();

    floatx4 acc[8][2];
#pragma unroll
    for (int mi = 0; mi < 8; ++mi)
#pragma unroll
        for (int ni = 0; ni < 2; ++ni)
            acc[mi][ni] = (floatx4){0.f, 0.f, 0.f, 0.f};

#pragma unroll
    for (int ks = 0; ks < 4; ++ks) {
        const int k0 = ks * 32 + quad * 8;
#pragma unroll
        for (int mi = 0; mi < 8; ++mi) {
            short8 a = *(const short8*)&Xs[mi * 16 + l15][k0];
            acc[mi][0] = __builtin_amdgcn_mfma_f32_16x16x32_bf16(a, bfrag[ks][0], acc[mi][0], 0, 0, 0);
            acc[mi][1] = __builtin_amdgcn_mfma_f32_16x16x32_bf16(a, bfrag[ks][1], acc[mi][1], 0, 0, 0);
        }
    }

    unsigned short* Hout = (w < 2) ? Abf : Bbf;
    const int colb = (w & 1) * 32;
#pragma unroll
    for (int mi = 0; mi < 8; ++mi)
#pragma unroll
        for (int ni = 0; ni < 2; ++ni)
#pragma unroll
            for (int r = 0; r < 4; ++r) {
                long long row = node0 + mi * 16 + quad * 4 + r;
                if (row < n_nodes)
                    Hout[row * OUT_CH + colb + ni * 16 + l15] = f2bf(acc[mi][ni][r]);
            }
}

// ---------------------------------------------------------------------------
// Kernel 3: segmented weighted gather-sum + epilogue.
// HALF-WAVE per node, 2 bf16 channels per lane (uint gather): one wave64
// gather instruction covers 2 edges. Per node, the in- and out-segments are
// concatenated into one stream with weights pre-scaled by Cin/Cout and an
// A-vs-B base offset per slot, so there is one inner loop and no LDS
// exchange. Edge (src,w) preloaded in 32-slot VGPR packs (coalesced loads),
// broadcast via __shfl (bpermute) -- no scalar loads in the dependency
// chain (the R5 regression). Unroll x4 keeps 4 gathers in flight.
// ---------------------------------------------------------------------------
__global__ __launch_bounds__(256)
void prop_kernel(const unsigned short* __restrict__ H,   // A base; B = A + Boff
                 const int* __restrict__ rpIn, const int* __restrict__ rpOut,
                 const int* __restrict__ srcIn, const float* __restrict__ ewIn,
                 const int* __restrict__ srcOut, const float* __restrict__ ewOut,
                 const float* __restrict__ bmi, const float* __restrict__ bmo,
                 const float* __restrict__ bsi, const float* __restrict__ bso,
                 const float* __restrict__ Cin, const float* __restrict__ Cout,
                 float* __restrict__ out, int n_nodes, int neIn, int neOut)
{
    const int lane  = threadIdx.x & 63;
    const int wv    = threadIdx.x >> 6;
    const int halfw = lane >> 5;          // 0 or 1: which node of the pair
    const int hl    = lane & 31;          // lane within half
    const int ch2   = hl * 2;             // first of my 2 channels

    const int t = ((int)blockIdx.x * 4 + wv) * 2 + halfw;
    const bool valid = (t < n_nodes);
    const int tc = valid ? t : 0;

    const int Boff = n_nodes * OUT_CH;    // element offset of B within H

    // Segment bounds (same value across each half; stays in VGPRs)
    int ei0 = rpIn[tc],  ei1 = rpIn[tc + 1];
    int eo0 = rpOut[tc], eo1 = rpOut[tc + 1];
    int dIn  = ei1 - ei0;
    int len  = valid ? (dIn + (eo1 - eo0)) : 0;
    float ci = Cin[tc], co = Cout[tc];

    // Wave-uniform max combined length across the two halves
    int l0 = __shfl(len, 0), l1 = __shfl(len, 32);
    int maxlen = __builtin_amdgcn_readfirstlane(max(l0, l1));

    float acc0 = 0.f, acc1 = 0.f;

    for (int p = 0; p < maxlen; p += 32) {
        // ---- pack load: slot j = p + hl of MY node's concatenated stream
        int j = p + hl;
        int iIn  = min(ei0 + max(0, min(j, dIn - 1)), neIn - 1);
        int jo   = j - dIn;
        int iOut = min(eo0 + max(0, jo), neOut - 1);
        int   sIn  = srcIn[iIn];
        float wIn  = ewIn[iIn];
        int   sOut = srcOut[iOut];
        float wOut = ewOut[iOut];
        bool inSeg  = (j < dIn);
        bool anySeg = (j < len);
        int   rowb = inSeg ? (sIn * OUT_CH) : (sOut * OUT_CH + Boff);
        rowb = anySeg ? rowb : 0;
        float wj = inSeg ? (ci * wIn) : (anySeg ? (co * wOut) : 0.f);

        // ---- inner: broadcast slots, gather 2ch per lane, 2 edges per iter
        int m = min(32, maxlen - p);
        for (int j2 = 0; j2 < m; j2 += 4) {
            int base = halfw * 32 + j2;
            int   r0 = __shfl(rowb, base + 0);
            int   r1 = __shfl(rowb, base + 1);
            int   r2 = __shfl(rowb, base + 2);
            int   r3 = __shfl(rowb, base + 3);
            float w0 = __shfl(wj, base + 0);
            float w1 = __shfl(wj, base + 1);
            float w2 = __shfl(wj, base + 2);
            float w3 = __shfl(wj, base + 3);
            unsigned u0 = *(const unsigned*)(H + r0 + ch2);
            unsigned u1 = *(const unsigned*)(H + r1 + ch2);
            unsigned u2 = *(const unsigned*)(H + r2 + ch2);
            unsigned u3 = *(const unsigned*)(H + r3 + ch2);
            // slots beyond a half's len have w==0 and row 0 -> safe no-ops
            acc0 += w0 * __uint_as_float(u0 << 16);
            acc1 += w0 * __uint_as_float(u0 & 0xffff0000u);
            acc0 += w1 * __uint_as_float(u1 << 16);
            acc1 += w1 * __uint_as_float(u1 & 0xffff0000u);
            acc0 += w2 * __uint_as_float(u2 << 16);
            acc1 += w2 * __uint_as_float(u2 & 0xffff0000u);
            acc0 += w3 * __uint_as_float(u3 << 16);
            acc1 += w3 * __uint_as_float(u3 & 0xffff0000u);
        }
    }

    if (valid) {
        // out = acc + ci*(bmi+bsi) + co*(bmo+bso), per 2 channels
        float2 bi = make_float2(bmi[ch2] + bsi[ch2], bmi[ch2 + 1] + bsi[ch2 + 1]);
        float2 bo = make_float2(bmo[ch2] + bso[ch2], bmo[ch2 + 1] + bso[ch2 + 1]);
        float2 o;
        o.x = acc0 + ci * bi.x + co * bo.x;
        o.y = acc1 + ci * bi.y + co * bo.y;
        *(float2*)(out + (long long)t * OUT_CH + ch2) = o;
    }
}

// ---------------------------------------------------------------------------
extern "C" void kernel_launch(void* const* d_in, const int* in_sizes, int n_in,
                              void* d_out, int out_size, void* d_ws, size_t ws_size,
                              hipStream_t stream)
{
    const float* x    = (const float*)d_in[0];
    const float* Wmi  = (const float*)d_in[1];
    const float* Wmo  = (const float*)d_in[2];
    const float* Wsh  = (const float*)d_in[3];
    const float* bmi  = (const float*)d_in[4];
    const float* bmo  = (const float*)d_in[5];
    const float* bsi  = (const float*)d_in[6];
    const float* bso  = (const float*)d_in[7];
    const float* Cin  = (const float*)d_in[8];
    const float* Cout = (const float*)d_in[9];
    const int*   eiIn  = (const int*)d_in[10];
    const float* ewIn  = (const float*)d_in[11];
    const int*   eiOut = (const int*)d_in[12];
    const float* ewOut = (const float*)d_in[13];

    const int n_nodes = in_sizes[0] / IN_CH;   // 100000
    const int neIn  = in_sizes[11];            // 1000000
    const int neOut = in_sizes[13];

    const int* srcIn  = eiIn;                  // edge_index[0]
    const int* tgtIn  = eiIn + neIn;           // edge_index[1] (sorted)
    const int* srcOut = eiOut;
    const int* tgtOut = eiOut + neOut;

    // Workspace layout: Abf|Bbf contiguous (bf16) | rpIn | rpOut | WcT (bf16)
    char* ws = (char*)d_ws;
    size_t NH = (size_t)n_nodes * OUT_CH * sizeof(unsigned short);
    unsigned short* Abf = (unsigned short*)ws;
    unsigned short* Bbf = (unsigned short*)(ws + NH);
    int* rpIn  = (int*)(ws + 2 * NH);
    int* rpOut = rpIn + (n_nodes + 1);
    unsigned short* WcT = (unsigned short*)(rpOut + (n_nodes + 1));

    // 1) rowptrs + combined-weight bf16 pre-pack
    int prep_threads = 2 * (n_nodes + 1) + 2 * OUT_CH * IN_CH;
    prep_kernel<<<(prep_threads + 255) / 256, 256, 0, stream>>>(
        tgtIn, tgtOut, Wmi, Wmo, Wsh, rpIn, rpOut, WcT, n_nodes, neIn, neOut);

    // 2) fused dense transform via MFMA (N=128 GEMM: [A|B] columns)
    int gblocks = (n_nodes + M_TILE - 1) / M_TILE;
    gemm_kernel<<<gblocks, 256, 0, stream>>>(x, WcT, Abf, Bbf, n_nodes);

    // 3) segmented gather-sum + epilogue (half-wave per node, 2 ch/lane)
    int pblocks = (n_nodes + 7) / 8;           // 8 nodes per block
    prop_kernel<<<pblocks, 256, 0, stream>>>(
        Abf, rpIn, rpOut, srcIn, ewIn, srcOut, ewOut,
        bmi, bmo, bsi, bso, Cin, Cout, (float*)d_out, n_nodes, neIn, neOut);
}

// Round 8
// 188.769 us; speedup vs baseline: 1.3502x; 1.0462x over previous
//
#include <hip/hip_runtime.h>

#define IN_CH   128
#define OUT_CH  64
#define M_TILE  128         // nodes per block in the MFMA GEMM
#define XS_PITCH 136        // 128 bf16 + 8 pad (272 B row) -> conflict-free frags

typedef __attribute__((ext_vector_type(8))) short short8;
typedef __attribute__((ext_vector_type(4))) float floatx4;

__device__ __forceinline__ unsigned short f2bf(float f) {
    union { float f; unsigned u; } v; v.f = f;
    unsigned r = v.u + 0x7fffu + ((v.u >> 16) & 1u);   // RNE
    return (unsigned short)(r >> 16);
}
__device__ __forceinline__ float bfl(unsigned u) {   // low bf16 -> f32
    return __uint_as_float(u << 16);
}
__device__ __forceinline__ float bfh(unsigned u) {   // high bf16 -> f32
    return __uint_as_float(u & 0xffff0000u);
}

// ---------------------------------------------------------------------------
// Kernel 1 (prep): CSR row pointers (lower_bound over sorted targets) for both
// edge sets, PLUS bf16 pre-pack of the combined transposed weights
// WcT[n][k] = bf16(Wc[k][n]), Wc = [Wmi+Ws | Wmo+Ws]  (128x128).
// ---------------------------------------------------------------------------
__global__ void prep_kernel(const int* __restrict__ tgtIn,
                            const int* __restrict__ tgtOut,
                            const float* __restrict__ Wmi,
                            const float* __restrict__ Wmo,
                            const float* __restrict__ Wsh,
                            int* __restrict__ rpIn,
                            int* __restrict__ rpOut,
                            unsigned short* __restrict__ WcT,
                            int n_nodes, int neIn, int neOut)
{
    int i = blockIdx.x * blockDim.x + threadIdx.x;
    int half = n_nodes + 1;
    if (i < 2 * half) {
        const int* tgt; int* rp; int t; int ne;
        if (i < half) { tgt = tgtIn;  rp = rpIn;  t = i;        ne = neIn; }
        else          { tgt = tgtOut; rp = rpOut; t = i - half; ne = neOut; }
        int lo = 0, hi = ne;
        while (lo < hi) {
            int mid = (lo + hi) >> 1;
            if (tgt[mid] < t) lo = mid + 1; else hi = mid;
        }
        rp[t] = lo;
    } else {
        int j = i - 2 * half;
        if (j < 2 * OUT_CH * IN_CH) {
            int n = j >> 7, k = j & 127;     // n: output col of Wc, k: input ch
            float m = (n < OUT_CH) ? Wmi[k * OUT_CH + n]
                                   : Wmo[k * OUT_CH + (n - OUT_CH)];
            float s = Wsh[k * OUT_CH + (n & (OUT_CH - 1))];
            WcT[n * IN_CH + k] = f2bf(m + s);
        }
    }
}

// ---------------------------------------------------------------------------
// Kernel 2 (MFMA GEMM): H = x_bf16 @ WcT^T. Block = 256 thr (4 waves),
// tile M=128 x N=128, K=128. Waves 0,1 -> A cols, waves 2,3 -> B cols.
// B-fragments straight from global WcT (32 KB, L2-hot); x tile via LDS.
// ---------------------------------------------------------------------------
__global__ __launch_bounds__(256, 3)
void gemm_kernel(const float* __restrict__ x,
                 const unsigned short* __restrict__ WcT,
                 unsigned short* __restrict__ Abf,
                 unsigned short* __restrict__ Bbf,
                 int n_nodes)
{
    __shared__ unsigned short Xs[M_TILE][XS_PITCH];   // 34.8 KB

    const int tid  = threadIdx.x;
    const int w    = tid >> 6;
    const int lane = tid & 63;
    const int l15  = lane & 15;
    const int quad = lane >> 4;
    const long long node0 = (long long)blockIdx.x * M_TILE;

    short8 bfrag[4][2];
#pragma unroll
    for (int ks = 0; ks < 4; ++ks)
#pragma unroll
        for (int ni = 0; ni < 2; ++ni)
            bfrag[ks][ni] = *(const short8*)&WcT[(w * 32 + ni * 16 + l15) * IN_CH
                                                 + ks * 32 + quad * 8];

    {
        const float4* x4 = (const float4*)x;
        for (int i = tid; i < M_TILE * (IN_CH / 4); i += 256) {
            int row = i >> 5, c4 = i & 31;
            long long node = node0 + row;
            float4 v = make_float4(0.f, 0.f, 0.f, 0.f);
            if (node < n_nodes) v = x4[node * (IN_CH / 4) + c4];
            uint2 p;
            p.x = ((unsigned)f2bf(v.y) << 16) | f2bf(v.x);
            p.y = ((unsigned)f2bf(v.w) << 16) | f2bf(v.z);
            *(uint2*)&Xs[row][c4 * 4] = p;
        }
    }
    __syncthreads();

    floatx4 acc[8][2];
#pragma unroll
    for (int mi = 0; mi < 8; ++mi)
#pragma unroll
        for (int ni = 0; ni < 2; ++ni)
            acc[mi][ni] = (floatx4){0.f, 0.f, 0.f, 0.f};

#pragma unroll
    for (int ks = 0; ks < 4; ++ks) {
        const int k0 = ks * 32 + quad * 8;
#pragma unroll
        for (int mi = 0; mi < 8; ++mi) {
            short8 a = *(const short8*)&Xs[mi * 16 + l15][k0];
            acc[mi][0] = __builtin_amdgcn_mfma_f32_16x16x32_bf16(a, bfrag[ks][0], acc[mi][0], 0, 0, 0);
            acc[mi][1] = __builtin_amdgcn_mfma_f32_16x16x32_bf16(a, bfrag[ks][1], acc[mi][1], 0, 0, 0);
        }
    }

    unsigned short* Hout = (w < 2) ? Abf : Bbf;
    const int colb = (w & 1) * 32;
#pragma unroll
    for (int mi = 0; mi < 8; ++mi)
#pragma unroll
        for (int ni = 0; ni < 2; ++ni)
#pragma unroll
            for (int r = 0; r < 4; ++r) {
                long long row = node0 + mi * 16 + quad * 4 + r;
                if (row < n_nodes)
                    Hout[row * OUT_CH + colb + ni * 16 + l15] = f2bf(acc[mi][ni][r]);
            }
}

// ---------------------------------------------------------------------------
// Kernel 3: segmented weighted gather-sum + epilogue.
// QUARTER-WAVE (16 lanes) per node, 4 bf16 channels/lane (uint2 gather):
// one wave64 gather instruction covers 4 edges (one per quarter).
// R7 BUG FIX: broadcast the BARE row base (no channel offset); each consumer
// lane adds its OWN ch4 via the hoisted per-lane pointer Hq = H + ch4.
// (R7 folded the producer lane's ch4 into rowb before __shfl -> absmax 43.)
// ---------------------------------------------------------------------------
__global__ __launch_bounds__(256)
void prop_kernel(const unsigned short* __restrict__ H,   // A base; B = A + Boff
                 const int* __restrict__ rpIn, const int* __restrict__ rpOut,
                 const int* __restrict__ srcIn, const float* __restrict__ ewIn,
                 const int* __restrict__ srcOut, const float* __restrict__ ewOut,
                 const float* __restrict__ bmi, const float* __restrict__ bmo,
                 const float* __restrict__ bsi, const float* __restrict__ bso,
                 const float* __restrict__ Cin, const float* __restrict__ Cout,
                 float* __restrict__ out, int n_nodes, int neIn, int neOut)
{
    const int lane = threadIdx.x & 63;
    const int wv   = threadIdx.x >> 6;
    const int q    = lane >> 4;           // quarter: which node of the four
    const int ql   = lane & 15;           // lane within quarter
    const int ch4  = ql * 4;              // first of my 4 channels
    const int qb   = lane & 48;           // quarter base lane

    const unsigned short* Hq = H + ch4;   // per-lane channel-offset base

    const int t = ((int)blockIdx.x * 4 + wv) * 4 + q;
    const bool valid = (t < n_nodes);
    const int tc = valid ? t : 0;

    const int Boff = n_nodes * OUT_CH;    // element offset of B within H

    int ei0 = rpIn[tc],  ei1 = rpIn[tc + 1];
    int eo0 = rpOut[tc], eo1 = rpOut[tc + 1];
    int dIn  = ei1 - ei0;
    int len  = valid ? (dIn + (eo1 - eo0)) : 0;
    float ci = Cin[tc], co = Cout[tc];

    // Wave-uniform max combined length across the four quarters
    int l0 = __shfl(len, 0),  l1 = __shfl(len, 16);
    int l2 = __shfl(len, 32), l3 = __shfl(len, 48);
    int maxlen = __builtin_amdgcn_readfirstlane(max(max(l0, l1), max(l2, l3)));

    float a0 = 0.f, a1 = 0.f, a2 = 0.f, a3 = 0.f;

    for (int p = 0; p < maxlen; p += 16) {
        // ---- pack: slot j = p + ql of MY quarter's concatenated stream
        int j = p + ql;
        int iIn  = min(ei0 + max(0, min(j, dIn - 1)), neIn - 1);
        int jo   = j - dIn;
        int iOut = min(eo0 + max(0, jo), neOut - 1);
        int   sIn  = srcIn[iIn];
        float wIn  = ewIn[iIn];
        int   sOut = srcOut[iOut];
        float wOut = ewOut[iOut];
        bool inSeg  = (j < dIn);
        bool anySeg = (j < len);
        int   rowb = inSeg ? (sIn * OUT_CH) : (sOut * OUT_CH + Boff);
        rowb = anySeg ? rowb : 0;
        float wj = inSeg ? (ci * wIn) : (anySeg ? (co * wOut) : 0.f);

        // ---- inner: 4 slots per iter -> 4 gather instrs = 16 edges
        int m = min(16, maxlen - p);
        for (int j2 = 0; j2 < m; j2 += 4) {
            int   r0 = __shfl(rowb, qb + j2 + 0);
            int   r1 = __shfl(rowb, qb + j2 + 1);
            int   r2 = __shfl(rowb, qb + j2 + 2);
            int   r3 = __shfl(rowb, qb + j2 + 3);
            float w0 = __shfl(wj, qb + j2 + 0);
            float w1 = __shfl(wj, qb + j2 + 1);
            float w2 = __shfl(wj, qb + j2 + 2);
            float w3 = __shfl(wj, qb + j2 + 3);
            uint2 u0 = *(const uint2*)(Hq + r0);
            uint2 u1 = *(const uint2*)(Hq + r1);
            uint2 u2 = *(const uint2*)(Hq + r2);
            uint2 u3 = *(const uint2*)(Hq + r3);
            // pad slots have w==0, row 0 -> safe no-ops
            a0 += w0 * bfl(u0.x); a1 += w0 * bfh(u0.x);
            a2 += w0 * bfl(u0.y); a3 += w0 * bfh(u0.y);
            a0 += w1 * bfl(u1.x); a1 += w1 * bfh(u1.x);
            a2 += w1 * bfl(u1.y); a3 += w1 * bfh(u1.y);
            a0 += w2 * bfl(u2.x); a1 += w2 * bfh(u2.x);
            a2 += w2 * bfl(u2.y); a3 += w2 * bfh(u2.y);
            a0 += w3 * bfl(u3.x); a1 += w3 * bfh(u3.x);
            a2 += w3 * bfl(u3.y); a3 += w3 * bfh(u3.y);
        }
    }

    if (valid) {
        float4 o;
        o.x = a0 + ci * (bmi[ch4 + 0] + bsi[ch4 + 0]) + co * (bmo[ch4 + 0] + bso[ch4 + 0]);
        o.y = a1 + ci * (bmi[ch4 + 1] + bsi[ch4 + 1]) + co * (bmo[ch4 + 1] + bso[ch4 + 1]);
        o.z = a2 + ci * (bmi[ch4 + 2] + bsi[ch4 + 2]) + co * (bmo[ch4 + 2] + bso[ch4 + 2]);
        o.w = a3 + ci * (bmi[ch4 + 3] + bsi[ch4 + 3]) + co * (bmo[ch4 + 3] + bso[ch4 + 3]);
        *(float4*)(out + (long long)t * OUT_CH + ch4) = o;
    }
}

// ---------------------------------------------------------------------------
extern "C" void kernel_launch(void* const* d_in, const int* in_sizes, int n_in,
                              void* d_out, int out_size, void* d_ws, size_t ws_size,
                              hipStream_t stream)
{
    const float* x    = (const float*)d_in[0];
    const float* Wmi  = (const float*)d_in[1];
    const float* Wmo  = (const float*)d_in[2];
    const float* Wsh  = (const float*)d_in[3];
    const float* bmi  = (const float*)d_in[4];
    const float* bmo  = (const float*)d_in[5];
    const float* bsi  = (const float*)d_in[6];
    const float* bso  = (const float*)d_in[7];
    const float* Cin  = (const float*)d_in[8];
    const float* Cout = (const float*)d_in[9];
    const int*   eiIn  = (const int*)d_in[10];
    const float* ewIn  = (const float*)d_in[11];
    const int*   eiOut = (const int*)d_in[12];
    const float* ewOut = (const float*)d_in[13];

    const int n_nodes = in_sizes[0] / IN_CH;   // 100000
    const int neIn  = in_sizes[11];            // 1000000
    const int neOut = in_sizes[13];

    const int* srcIn  = eiIn;                  // edge_index[0]
    const int* tgtIn  = eiIn + neIn;           // edge_index[1] (sorted)
    const int* srcOut = eiOut;
    const int* tgtOut = eiOut + neOut;

    // Workspace layout: Abf|Bbf contiguous (bf16) | rpIn | rpOut | WcT (bf16)
    char* ws = (char*)d_ws;
    size_t NH = (size_t)n_nodes * OUT_CH * sizeof(unsigned short);
    unsigned short* Abf = (unsigned short*)ws;
    unsigned short* Bbf = (unsigned short*)(ws + NH);
    int* rpIn  = (int*)(ws + 2 * NH);
    int* rpOut = rpIn + (n_nodes + 1);
    unsigned short* WcT = (unsigned short*)(rpOut + (n_nodes + 1));

    // 1) rowptrs + combined-weight bf16 pre-pack
    int prep_threads = 2 * (n_nodes + 1) + 2 * OUT_CH * IN_CH;
    prep_kernel<<<(prep_threads + 255) / 256, 256, 0, stream>>>(
        tgtIn, tgtOut, Wmi, Wmo, Wsh, rpIn, rpOut, WcT, n_nodes, neIn, neOut);

    // 2) fused dense transform via MFMA (N=128 GEMM: [A|B] columns)
    int gblocks = (n_nodes + M_TILE - 1) / M_TILE;
    gemm_kernel<<<gblocks, 256, 0, stream>>>(x, WcT, Abf, Bbf, n_nodes);

    // 3) segmented gather-sum + epilogue (quarter-wave per node, 4 ch/lane)
    int pblocks = (n_nodes + 15) / 16;         // 16 nodes per block
    prop_kernel<<<pblocks, 256, 0, stream>>>(
        Abf, rpIn, rpOut, srcIn, ewIn, srcOut, ewOut,
        bmi, bmo, bsi, bso, Cin, Cout, (float*)d_out, n_nodes, neIn, neOut);
}

// Round 9
// 187.711 us; speedup vs baseline: 1.3578x; 1.0056x over previous
//
#include <hip/hip_runtime.h>

#define IN_CH   128
#define OUT_CH  64
#define M_TILE  128         // nodes per block in the MFMA GEMM
#define XS_PITCH 136        // 128 bf16 + 8 pad (272 B row) -> conflict-free frags

typedef __attribute__((ext_vector_type(8))) short short8;
typedef __attribute__((ext_vector_type(4))) float floatx4;

__device__ __forceinline__ unsigned short f2bf(float f) {
    union { float f; unsigned u; } v; v.f = f;
    unsigned r = v.u + 0x7fffu + ((v.u >> 16) & 1u);   // RNE
    return (unsigned short)(r >> 16);
}
__device__ __forceinline__ float bfl(unsigned u) {   // low bf16 -> f32
    return __uint_as_float(u << 16);
}
__device__ __forceinline__ float bfh(unsigned u) {   // high bf16 -> f32
    return __uint_as_float(u & 0xffff0000u);
}

// ---------------------------------------------------------------------------
// Kernel 1 (prep): CSR row pointers (lower_bound over sorted targets) for both
// edge sets, PLUS bf16 pre-pack of the combined transposed weights
// WcT[n][k] = bf16(Wc[k][n]), Wc = [Wmi+Ws | Wmo+Ws]  (128x128).
// ---------------------------------------------------------------------------
__global__ void prep_kernel(const int* __restrict__ tgtIn,
                            const int* __restrict__ tgtOut,
                            const float* __restrict__ Wmi,
                            const float* __restrict__ Wmo,
                            const float* __restrict__ Wsh,
                            int* __restrict__ rpIn,
                            int* __restrict__ rpOut,
                            unsigned short* __restrict__ WcT,
                            int n_nodes, int neIn, int neOut)
{
    int i = blockIdx.x * blockDim.x + threadIdx.x;
    int half = n_nodes + 1;
    if (i < 2 * half) {
        const int* tgt; int* rp; int t; int ne;
        if (i < half) { tgt = tgtIn;  rp = rpIn;  t = i;        ne = neIn; }
        else          { tgt = tgtOut; rp = rpOut; t = i - half; ne = neOut; }
        int lo = 0, hi = ne;
        while (lo < hi) {
            int mid = (lo + hi) >> 1;
            if (tgt[mid] < t) lo = mid + 1; else hi = mid;
        }
        rp[t] = lo;
    } else {
        int j = i - 2 * half;
        if (j < 2 * OUT_CH * IN_CH) {
            int n = j >> 7, k = j & 127;     // n: output col of Wc, k: input ch
            float m = (n < OUT_CH) ? Wmi[k * OUT_CH + n]
                                   : Wmo[k * OUT_CH + (n - OUT_CH)];
            float s = Wsh[k * OUT_CH + (n & (OUT_CH - 1))];
            WcT[n * IN_CH + k] = f2bf(m + s);
        }
    }
}

// ---------------------------------------------------------------------------
// Kernel 2 (MFMA GEMM): H = x_bf16 @ WcT^T. Block = 256 thr (4 waves),
// tile M=128 x N=128, K=128. Waves 0,1 -> A cols, waves 2,3 -> B cols.
// B-fragments straight from global WcT (32 KB, L2-hot); x tile via LDS.
// ---------------------------------------------------------------------------
__global__ __launch_bounds__(256, 3)
void gemm_kernel(const float* __restrict__ x,
                 const unsigned short* __restrict__ WcT,
                 unsigned short* __restrict__ Abf,
                 unsigned short* __restrict__ Bbf,
                 int n_nodes)
{
    __shared__ unsigned short Xs[M_TILE][XS_PITCH];   // 34.8 KB

    const int tid  = threadIdx.x;
    const int w    = tid >> 6;
    const int lane = tid & 63;
    const int l15  = lane & 15;
    const int quad = lane >> 4;
    const long long node0 = (long long)blockIdx.x * M_TILE;

    short8 bfrag[4][2];
#pragma unroll
    for (int ks = 0; ks < 4; ++ks)
#pragma unroll
        for (int ni = 0; ni < 2; ++ni)
            bfrag[ks][ni] = *(const short8*)&WcT[(w * 32 + ni * 16 + l15) * IN_CH
                                                 + ks * 32 + quad * 8];

    {
        const float4* x4 = (const float4*)x;
        for (int i = tid; i < M_TILE * (IN_CH / 4); i += 256) {
            int row = i >> 5, c4 = i & 31;
            long long node = node0 + row;
            float4 v = make_float4(0.f, 0.f, 0.f, 0.f);
            if (node < n_nodes) v = x4[node * (IN_CH / 4) + c4];
            uint2 p;
            p.x = ((unsigned)f2bf(v.y) << 16) | f2bf(v.x);
            p.y = ((unsigned)f2bf(v.w) << 16) | f2bf(v.z);
            *(uint2*)&Xs[row][c4 * 4] = p;
        }
    }
    __syncthreads();

    floatx4 acc[8][2];
#pragma unroll
    for (int mi = 0; mi < 8; ++mi)
#pragma unroll
        for (int ni = 0; ni < 2; ++ni)
            acc[mi][ni] = (floatx4){0.f, 0.f, 0.f, 0.f};

#pragma unroll
    for (int ks = 0; ks < 4; ++ks) {
        const int k0 = ks * 32 + quad * 8;
#pragma unroll
        for (int mi = 0; mi < 8; ++mi) {
            short8 a = *(const short8*)&Xs[mi * 16 + l15][k0];
            acc[mi][0] = __builtin_amdgcn_mfma_f32_16x16x32_bf16(a, bfrag[ks][0], acc[mi][0], 0, 0, 0);
            acc[mi][1] = __builtin_amdgcn_mfma_f32_16x16x32_bf16(a, bfrag[ks][1], acc[mi][1], 0, 0, 0);
        }
    }

    unsigned short* Hout = (w < 2) ? Abf : Bbf;
    const int colb = (w & 1) * 32;
#pragma unroll
    for (int mi = 0; mi < 8; ++mi)
#pragma unroll
        for (int ni = 0; ni < 2; ++ni)
#pragma unroll
            for (int r = 0; r < 4; ++r) {
                long long row = node0 + mi * 16 + quad * 4 + r;
                if (row < n_nodes)
                    Hout[row * OUT_CH + colb + ni * 16 + l15] = f2bf(acc[mi][ni][r]);
            }
}

// ---------------------------------------------------------------------------
// Kernel 3: segmented weighted gather-sum + epilogue.
// EIGHTH-WAVE (8 lanes) per node, 8 bf16 channels/lane (uint4 gather): one
// wave64 gather instruction covers 8 edges; the full 8-slot pack is processed
// unconditionally (pad slots have w=0, row 0 -> no-ops), so 8 gathers
// (64 rows) are in flight per wave. Next pack's (src,w) loads are prefetched
// before the gather body so the edge-stream latency is off the serial chain.
// Broadcast the BARE row base; each lane adds its own ch8 via Hq (R7 lesson).
// ---------------------------------------------------------------------------
__global__ __launch_bounds__(256)
void prop_kernel(const unsigned short* __restrict__ H,   // A base; B = A + Boff
                 const int* __restrict__ rpIn, const int* __restrict__ rpOut,
                 const int* __restrict__ srcIn, const float* __restrict__ ewIn,
                 const int* __restrict__ srcOut, const float* __restrict__ ewOut,
                 const float* __restrict__ bmi, const float* __restrict__ bmo,
                 const float* __restrict__ bsi, const float* __restrict__ bso,
                 const float* __restrict__ Cin, const float* __restrict__ Cout,
                 float* __restrict__ out, int n_nodes, int neIn, int neOut)
{
    const int lane = threadIdx.x & 63;
    const int wv   = threadIdx.x >> 6;
    const int e    = lane >> 3;           // eighth: which node of the eight
    const int el   = lane & 7;            // lane within eighth
    const int ch8  = el * 8;              // first of my 8 channels
    const int eb   = lane & 56;           // eighth base lane

    const unsigned short* Hq = H + ch8;   // per-lane channel-offset base

    const int t = ((int)blockIdx.x * 4 + wv) * 8 + e;
    const bool valid = (t < n_nodes);
    const int tc = valid ? t : 0;

    const int Boff = n_nodes * OUT_CH;    // element offset of B within H

    int ei0 = rpIn[tc],  ei1 = rpIn[tc + 1];
    int eo0 = rpOut[tc], eo1 = rpOut[tc + 1];
    int dIn  = ei1 - ei0;
    int len  = valid ? (dIn + (eo1 - eo0)) : 0;
    float ci = Cin[tc], co = Cout[tc];

    // Wave-uniform max combined length across the eight eighths (butterfly)
    int ml = len;
    ml = max(ml, __shfl_xor(ml, 8));
    ml = max(ml, __shfl_xor(ml, 16));
    ml = max(ml, __shfl_xor(ml, 32));
    const int maxlen = __builtin_amdgcn_readfirstlane(ml);

    float a0 = 0.f, a1 = 0.f, a2 = 0.f, a3 = 0.f;
    float a4 = 0.f, a5 = 0.f, a6 = 0.f, a7 = 0.f;

    // ---- raw pack loader: slot j of MY eighth's concatenated stream
    auto load_raw = [&](int j, int& sI, float& wI, int& sO, float& wO) {
        int iIn  = min(ei0 + max(0, min(j, dIn - 1)), neIn - 1);
        int jo   = j - dIn;
        int iOut = min(eo0 + max(0, jo), neOut - 1);
        sI = srcIn[iIn];  wI = ewIn[iIn];
        sO = srcOut[iOut]; wO = ewOut[iOut];
    };

    int   sI, sO;  float wI, wO;
    load_raw(el, sI, wI, sO, wO);       // pack 0

    for (int p = 0; p < maxlen; p += 8) {
        // ---- convert current raws to (rowb, wj)
        int j = p + el;
        bool inSeg  = (j < dIn);
        bool anySeg = (j < len);
        int   rowb = inSeg ? (sI * OUT_CH) : (sO * OUT_CH + Boff);
        rowb = anySeg ? rowb : 0;
        float wj = inSeg ? (ci * wI) : (anySeg ? (co * wO) : 0.f);

        // ---- prefetch next pack's raws (latency hidden by gather body)
        if (p + 8 < maxlen)
            load_raw(p + 8 + el, sI, wI, sO, wO);

        // ---- gather body: 8 slots, 8 uint4 gathers in flight (64 rows)
        int   r0 = __shfl(rowb, eb + 0), r1 = __shfl(rowb, eb + 1);
        int   r2 = __shfl(rowb, eb + 2), r3 = __shfl(rowb, eb + 3);
        int   r4 = __shfl(rowb, eb + 4), r5 = __shfl(rowb, eb + 5);
        int   r6 = __shfl(rowb, eb + 6), r7 = __shfl(rowb, eb + 7);
        float w0 = __shfl(wj, eb + 0), w1 = __shfl(wj, eb + 1);
        float w2 = __shfl(wj, eb + 2), w3 = __shfl(wj, eb + 3);
        float w4 = __shfl(wj, eb + 4), w5 = __shfl(wj, eb + 5);
        float w6 = __shfl(wj, eb + 6), w7 = __shfl(wj, eb + 7);
        uint4 u0 = *(const uint4*)(Hq + r0);
        uint4 u1 = *(const uint4*)(Hq + r1);
        uint4 u2 = *(const uint4*)(Hq + r2);
        uint4 u3 = *(const uint4*)(Hq + r3);
        uint4 u4 = *(const uint4*)(Hq + r4);
        uint4 u5 = *(const uint4*)(Hq + r5);
        uint4 u6 = *(const uint4*)(Hq + r6);
        uint4 u7 = *(const uint4*)(Hq + r7);
        // pad slots have w==0, row 0 -> safe no-ops
        a0 += w0 * bfl(u0.x); a1 += w0 * bfh(u0.x); a2 += w0 * bfl(u0.y); a3 += w0 * bfh(u0.y);
        a4 += w0 * bfl(u0.z); a5 += w0 * bfh(u0.z); a6 += w0 * bfl(u0.w); a7 += w0 * bfh(u0.w);
        a0 += w1 * bfl(u1.x); a1 += w1 * bfh(u1.x); a2 += w1 * bfl(u1.y); a3 += w1 * bfh(u1.y);
        a4 += w1 * bfl(u1.z); a5 += w1 * bfh(u1.z); a6 += w1 * bfl(u1.w); a7 += w1 * bfh(u1.w);
        a0 += w2 * bfl(u2.x); a1 += w2 * bfh(u2.x); a2 += w2 * bfl(u2.y); a3 += w2 * bfh(u2.y);
        a4 += w2 * bfl(u2.z); a5 += w2 * bfh(u2.z); a6 += w2 * bfl(u2.w); a7 += w2 * bfh(u2.w);
        a0 += w3 * bfl(u3.x); a1 += w3 * bfh(u3.x); a2 += w3 * bfl(u3.y); a3 += w3 * bfh(u3.y);
        a4 += w3 * bfl(u3.z); a5 += w3 * bfh(u3.z); a6 += w3 * bfl(u3.w); a7 += w3 * bfh(u3.w);
        a0 += w4 * bfl(u4.x); a1 += w4 * bfh(u4.x); a2 += w4 * bfl(u4.y); a3 += w4 * bfh(u4.y);
        a4 += w4 * bfl(u4.z); a5 += w4 * bfh(u4.z); a6 += w4 * bfl(u4.w); a7 += w4 * bfh(u4.w);
        a0 += w5 * bfl(u5.x); a1 += w5 * bfh(u5.x); a2 += w5 * bfl(u5.y); a3 += w5 * bfh(u5.y);
        a4 += w5 * bfl(u5.z); a5 += w5 * bfh(u5.z); a6 += w5 * bfl(u5.w); a7 += w5 * bfh(u5.w);
        a0 += w6 * bfl(u6.x); a1 += w6 * bfh(u6.x); a2 += w6 * bfl(u6.y); a3 += w6 * bfh(u6.y);
        a4 += w6 * bfl(u6.z); a5 += w6 * bfh(u6.z); a6 += w6 * bfl(u6.w); a7 += w6 * bfh(u6.w);
        a0 += w7 * bfl(u7.x); a1 += w7 * bfh(u7.x); a2 += w7 * bfl(u7.y); a3 += w7 * bfh(u7.y);
        a4 += w7 * bfl(u7.z); a5 += w7 * bfh(u7.z); a6 += w7 * bfl(u7.w); a7 += w7 * bfh(u7.w);
    }

    if (valid) {
        float4 o0, o1;
        o0.x = a0 + ci * (bmi[ch8 + 0] + bsi[ch8 + 0]) + co * (bmo[ch8 + 0] + bso[ch8 + 0]);
        o0.y = a1 + ci * (bmi[ch8 + 1] + bsi[ch8 + 1]) + co * (bmo[ch8 + 1] + bso[ch8 + 1]);
        o0.z = a2 + ci * (bmi[ch8 + 2] + bsi[ch8 + 2]) + co * (bmo[ch8 + 2] + bso[ch8 + 2]);
        o0.w = a3 + ci * (bmi[ch8 + 3] + bsi[ch8 + 3]) + co * (bmo[ch8 + 3] + bso[ch8 + 3]);
        o1.x = a4 + ci * (bmi[ch8 + 4] + bsi[ch8 + 4]) + co * (bmo[ch8 + 4] + bso[ch8 + 4]);
        o1.y = a5 + ci * (bmi[ch8 + 5] + bsi[ch8 + 5]) + co * (bmo[ch8 + 5] + bso[ch8 + 5]);
        o1.z = a6 + ci * (bmi[ch8 + 6] + bsi[ch8 + 6]) + co * (bmo[ch8 + 6] + bso[ch8 + 6]);
        o1.w = a7 + ci * (bmi[ch8 + 7] + bsi[ch8 + 7]) + co * (bmo[ch8 + 7] + bso[ch8 + 7]);
        float* ob = out + (long long)t * OUT_CH + ch8;
        *(float4*)ob = o0;
        *(float4*)(ob + 4) = o1;
    }
}

// ---------------------------------------------------------------------------
extern "C" void kernel_launch(void* const* d_in, const int* in_sizes, int n_in,
                              void* d_out, int out_size, void* d_ws, size_t ws_size,
                              hipStream_t stream)
{
    const float* x    = (const float*)d_in[0];
    const float* Wmi  = (const float*)d_in[1];
    const float* Wmo  = (const float*)d_in[2];
    const float* Wsh  = (const float*)d_in[3];
    const float* bmi  = (const float*)d_in[4];
    const float* bmo  = (const float*)d_in[5];
    const float* bsi  = (const float*)d_in[6];
    const float* bso  = (const float*)d_in[7];
    const float* Cin  = (const float*)d_in[8];
    const float* Cout = (const float*)d_in[9];
    const int*   eiIn  = (const int*)d_in[10];
    const float* ewIn  = (const float*)d_in[11];
    const int*   eiOut = (const int*)d_in[12];
    const float* ewOut = (const float*)d_in[13];

    const int n_nodes = in_sizes[0] / IN_CH;   // 100000
    const int neIn  = in_sizes[11];            // 1000000
    const int neOut = in_sizes[13];

    const int* srcIn  = eiIn;                  // edge_index[0]
    const int* tgtIn  = eiIn + neIn;           // edge_index[1] (sorted)
    const int* srcOut = eiOut;
    const int* tgtOut = eiOut + neOut;

    // Workspace layout: Abf|Bbf contiguous (bf16) | rpIn | rpOut | WcT (bf16)
    char* ws = (char*)d_ws;
    size_t NH = (size_t)n_nodes * OUT_CH * sizeof(unsigned short);
    unsigned short* Abf = (unsigned short*)ws;
    unsigned short* Bbf = (unsigned short*)(ws + NH);
    int* rpIn  = (int*)(ws + 2 * NH);
    int* rpOut = rpIn + (n_nodes + 1);
    unsigned short* WcT = (unsigned short*)(rpOut + (n_nodes + 1));

    // 1) rowptrs + combined-weight bf16 pre-pack
    int prep_threads = 2 * (n_nodes + 1) + 2 * OUT_CH * IN_CH;
    prep_kernel<<<(prep_threads + 255) / 256, 256, 0, stream>>>(
        tgtIn, tgtOut, Wmi, Wmo, Wsh, rpIn, rpOut, WcT, n_nodes, neIn, neOut);

    // 2) fused dense transform via MFMA (N=128 GEMM: [A|B] columns)
    int gblocks = (n_nodes + M_TILE - 1) / M_TILE;
    gemm_kernel<<<gblocks, 256, 0, stream>>>(x, WcT, Abf, Bbf, n_nodes);

    // 3) segmented gather-sum + epilogue (eighth-wave per node, 8 ch/lane)
    int pblocks = (n_nodes + 31) / 32;         // 32 nodes per block
    prop_kernel<<<pblocks, 256, 0, stream>>>(
        Abf, rpIn, rpOut, srcIn, ewIn, srcOut, ewOut,
        bmi, bmo, bsi, bso, Cin, Cout, (float*)d_out, n_nodes, neIn, neOut);
}